// Round 2
// baseline (505.829 us; speedup 1.0000x reference)
//
#include <hip/hip_runtime.h>

// PillarMaxPooling: Linear(10->64,no bias) -> BN1d(eval,eps=1e-3) -> ReLU ->
// segment_max -> clamp0.
//
// R1 finding: atomicMax version is atomic-count bound (128M device-scope
// atomics = 500 MB of 4B write-requests past L2, ~400 G atomic/s ceiling).
// R2: counting-sort points into CSR by pillar (4M small int atomics on an
// 800KB L2-resident array), then a gather kernel with ONE wave per pillar,
// lane = output channel, zero atomics, one coalesced 256B store per pillar.

#define C_IN   10
#define C_OUT  64
#define BLOCK  256
#define CHUNK  1024    // counts items per scan block
#define SCAN_T 256

// ---------- K1: histogram of pillar ids ----------
__global__ __launch_bounds__(256)
void k_hist(const int* __restrict__ idx, int* __restrict__ counts, int P) {
    int p = blockIdx.x * 256 + threadIdx.x;
    if (p < P) atomicAdd(&counts[idx[p]], 1);
}

// ---------- block exclusive scan helper (256 threads) ----------
__device__ __forceinline__ int block_exscan(int v, int* s) {
    int t = threadIdx.x;
    s[t] = v; __syncthreads();
#pragma unroll
    for (int off = 1; off < SCAN_T; off <<= 1) {
        int x = (t >= off) ? s[t - off] : 0;
        __syncthreads();
        s[t] += x;
        __syncthreads();
    }
    return s[t] - v;   // exclusive prefix
}

// ---------- K2a: per-block chunk sums ----------
__global__ __launch_bounds__(SCAN_T)
void k_scan_partial(const int* __restrict__ counts, int* __restrict__ blockSums, int M) {
    __shared__ int s[SCAN_T];
    int i0 = blockIdx.x * CHUNK + threadIdx.x * 4;
    int tot = 0;
#pragma unroll
    for (int i = 0; i < 4; ++i) { int id = i0 + i; if (id < M) tot += counts[id]; }
    int ex = block_exscan(tot, s);
    if (threadIdx.x == SCAN_T - 1) blockSums[blockIdx.x] = ex + tot;
}

// ---------- K2b: scan the (<=256) block sums in one block ----------
__global__ __launch_bounds__(SCAN_T)
void k_scan_tops(int* __restrict__ blockSums, int NB) {
    __shared__ int s[SCAN_T];
    int t = threadIdx.x;
    int v = (t < NB) ? blockSums[t] : 0;
    int ex = block_exscan(v, s);
    if (t < NB) blockSums[t] = ex;
}

// ---------- K2c: write offsets (immutable) + cursor (mutable copy) ----------
__global__ __launch_bounds__(SCAN_T)
void k_scan_write(const int* __restrict__ counts, const int* __restrict__ blockSums,
                  int* __restrict__ offsets, int* __restrict__ cursor, int M) {
    __shared__ int s[SCAN_T];
    int base = blockSums[blockIdx.x];
    int i0 = blockIdx.x * CHUNK + threadIdx.x * 4;
    int c[4]; int tot = 0;
#pragma unroll
    for (int i = 0; i < 4; ++i) { int id = i0 + i; c[i] = (id < M) ? counts[id] : 0; tot += c[i]; }
    int ex = block_exscan(tot, s) + base;
#pragma unroll
    for (int i = 0; i < 4; ++i) {
        int id = i0 + i;
        if (id < M) { offsets[id] = ex; cursor[id] = ex; }
        ex += c[i];
    }
}

// ---------- K3: scatter point ids into CSR order ----------
__global__ __launch_bounds__(256)
void k_scatter(const int* __restrict__ idx, int* __restrict__ cursor,
               int* __restrict__ sorted, int P) {
    int p = blockIdx.x * 256 + threadIdx.x;
    if (p < P) {
        int pos = atomicAdd(&cursor[idx[p]], 1);
        sorted[pos] = p;
    }
}

// ---------- K4: gather + fused Linear/BN/ReLU/max, one wave per pillar ----------
__device__ __forceinline__ float bcast(float v, int srclane) {
    return __int_as_float(__builtin_amdgcn_readlane(__float_as_int(v), srclane));
}

__global__ __launch_bounds__(BLOCK)
void k_pool(const float* __restrict__ gf,
            const int*   __restrict__ sorted,
            const int*   __restrict__ offsets,
            const int*   __restrict__ counts,
            const float* __restrict__ W,
            const float* __restrict__ gamma,
            const float* __restrict__ beta,
            const float* __restrict__ rmean,
            const float* __restrict__ rvar,
            float*       __restrict__ out,
            int M)
{
    const int lane = threadIdx.x & 63;
    const int m = blockIdx.x * (BLOCK >> 6) + (threadIdx.x >> 6);   // pillar id
    if (m >= M) return;

    // lane == output channel: weights + folded BN in registers
    float w[C_IN];
#pragma unroll
    for (int k = 0; k < C_IN; ++k) w[k] = W[k * C_OUT + lane];
    const float inv_std = gamma[lane] * rsqrtf(rvar[lane] + 1e-3f);
    const float bias    = fmaf(-rmean[lane], inv_std, beta[lane]);

    const int start = offsets[m];
    const int cnt   = counts[m];

    // lane -> (point-in-group g = lane/10, feature f = lane%10)
    const int g = (lane * 205) >> 11;        // exact lane/10 for lane in [0,63]
    const int f = lane - g * 10;

    float acc = 0.0f;                        // >=0 running max (handles empty + clamp0)
    for (int b = 0; b < cnt; b += 6) {
        const int nb = min(6, cnt - b);      // wave-uniform
        float xv = 0.0f;
        if (lane < nb * C_IN) {
            const int pid = sorted[start + b + g];
            xv = gf[pid * C_IN + f];
        }
#pragma unroll
        for (int j = 0; j < 6; ++j) {
            if (j >= nb) break;              // wave-uniform
            float y = 0.0f;
#pragma unroll
            for (int k = 0; k < C_IN; ++k)
                y = fmaf(bcast(xv, j * C_IN + k), w[k], y);
            const float h = fmaf(y, inv_std, bias);   // BN affine
            acc = fmaxf(acc, h);             // relu folded: acc>=0 always
        }
    }
    out[m * C_OUT + lane] = acc;             // coalesced 256B per wave
}

extern "C" void kernel_launch(void* const* d_in, const int* in_sizes, int n_in,
                              void* d_out, int out_size, void* d_ws, size_t ws_size,
                              hipStream_t stream) {
    const float* gf    = (const float*)d_in[0];
    const int*   idx   = (const int*)  d_in[1];
    const float* W     = (const float*)d_in[3];
    const float* gamma = (const float*)d_in[4];
    const float* beta  = (const float*)d_in[5];
    const float* rmean = (const float*)d_in[6];
    const float* rvar  = (const float*)d_in[7];
    float*       out   = (float*)d_out;

    const int P = in_sizes[0] / C_IN;
    const int M = out_size / C_OUT;

    // workspace layout (256B-aligned regions)
    char* ws = (char*)d_ws;
    auto align256 = [](size_t x) { return (x + 255) & ~(size_t)255; };
    int* counts    = (int*)ws;                 ws += align256((size_t)M * 4);
    int* offsets   = (int*)ws;                 ws += align256((size_t)M * 4);
    int* cursor    = (int*)ws;                 ws += align256((size_t)M * 4);
    int* blockSums = (int*)ws;                 ws += align256((size_t)SCAN_T * 4);
    int* sorted    = (int*)ws;                 /* P ints */

    const int NB = (M + CHUNK - 1) / CHUNK;    // 196 for M=200k (<=256 required)

    hipMemsetAsync(counts, 0, (size_t)M * 4, stream);
    k_hist       <<<(P + 255) / 256, 256, 0, stream>>>(idx, counts, P);
    k_scan_partial<<<NB, SCAN_T, 0, stream>>>(counts, blockSums, M);
    k_scan_tops  <<<1,  SCAN_T, 0, stream>>>(blockSums, NB);
    k_scan_write <<<NB, SCAN_T, 0, stream>>>(counts, blockSums, offsets, cursor, M);
    k_scatter    <<<(P + 255) / 256, 256, 0, stream>>>(idx, cursor, sorted, P);
    k_pool       <<<(M + (BLOCK >> 6) - 1) / (BLOCK >> 6), BLOCK, 0, stream>>>(
                     gf, sorted, offsets, counts, W, gamma, beta, rmean, rvar, out, M);
}

// Round 3
// 436.428 us; speedup vs baseline: 1.1590x; 1.1590x over previous
//
#include <hip/hip_runtime.h>

// PillarMaxPooling: Linear(10->64,nobias) -> BN1d(eval,eps=1e-3) -> ReLU ->
// segment_max -> clamp0.
//
// R1: 128M global atomicMax = atomic/write-path bound (322 us).
// R2: naive scatter sort: 4.4 GB FETCH from cross-XCD line ping-pong on
//     random 4B global RMW (180 us for scatter alone).
// R3: bucket points into 782 coarse buckets (256 pillars each) with an
//     LDS-staged multisplit (no per-point global atomics, run-grouped writes),
//     then pool with one block per bucket using a 64 KB LDS accumulator and
//     LDS atomicMax; single coalesced 64 KB store per block.

#define C_IN   10
#define C_OUT  64
#define BSHIFT 8
#define BPILL  (1 << BSHIFT)     // pillars per bucket
#define MAXNB  1024              // supports M <= 262144
#define CHUNK  8192              // points per multisplit block
#define PPW    12                // points per wave-iteration in pool

// ---------------- K0: global bucket histogram (LDS-privatized) ----------------
__global__ __launch_bounds__(256)
void k_hist(const int* __restrict__ idx, int* __restrict__ ghist, int P, int NB) {
    __shared__ int lh[MAXNB];
    for (int b = threadIdx.x; b < NB; b += 256) lh[b] = 0;
    __syncthreads();
    const int base = blockIdx.x * CHUNK;
    for (int i = 0; i < CHUNK / 256; ++i) {
        int p = base + i * 256 + threadIdx.x;
        if (p < P) atomicAdd(&lh[idx[p] >> BSHIFT], 1);
    }
    __syncthreads();
    for (int b = threadIdx.x; b < NB; b += 256) {
        int h = lh[b];
        if (h) atomicAdd(&ghist[b], h);
    }
}

// ---------------- K1: scan bucket hist -> starts[NB+1] + cursor ----------------
// cursor aliases ghist (in-place convert); 1 block, 256 threads, 4 entries each.
__global__ __launch_bounds__(256)
void k_scan(int* __restrict__ ghist_cursor, int* __restrict__ starts, int NB) {
    __shared__ int tmp[256];
    const int t = threadIdx.x;
    int c[4]; int tot = 0;
#pragma unroll
    for (int j = 0; j < 4; ++j) {
        int e = t * 4 + j;
        c[j] = (e < NB) ? ghist_cursor[e] : 0;
        tot += c[j];
    }
    tmp[t] = tot; __syncthreads();
#pragma unroll
    for (int off = 1; off < 256; off <<= 1) {
        int x = (t >= off) ? tmp[t - off] : 0;
        __syncthreads();
        tmp[t] += x;
        __syncthreads();
    }
    int ex = tmp[t] - tot;
#pragma unroll
    for (int j = 0; j < 4; ++j) {
        int e = t * 4 + j;
        if (e < NB) { starts[e] = ex; ghist_cursor[e] = ex; }
        ex += c[j];
        if (e == NB - 1) starts[NB] = ex;
    }
}

// ---------------- K2: multisplit with LDS staging, run-grouped writes ----------
__global__ __launch_bounds__(256)
void k_split(const int* __restrict__ idx, int* __restrict__ cursor,
             unsigned int* __restrict__ sorted, int P, int NB) {
    __shared__ int lstart[MAXNB];
    __shared__ int lcur[MAXNB];
    __shared__ int rbase[MAXNB];
    __shared__ unsigned int stage[CHUNK];
    __shared__ int tmp[256];
    const int t = threadIdx.x;
    const int base = blockIdx.x * CHUNK;

    // P1: local histogram in lcur
    for (int b = t; b < NB; b += 256) lcur[b] = 0;
    __syncthreads();
    for (int i = 0; i < CHUNK / 256; ++i) {
        int p = base + i * 256 + t;
        if (p < P) atomicAdd(&lcur[idx[p] >> BSHIFT], 1);
    }
    __syncthreads();

    // P2: local exclusive scan of lcur -> lstart
    int c[4]; int tot = 0;
#pragma unroll
    for (int j = 0; j < 4; ++j) {
        int e = t * 4 + j;
        c[j] = (e < NB) ? lcur[e] : 0;
        tot += c[j];
    }
    tmp[t] = tot; __syncthreads();
#pragma unroll
    for (int off = 1; off < 256; off <<= 1) {
        int x = (t >= off) ? tmp[t - off] : 0;
        __syncthreads();
        tmp[t] += x;
        __syncthreads();
    }
    int ex = tmp[t] - tot;
#pragma unroll
    for (int j = 0; j < 4; ++j) {
        int e = t * 4 + j;
        if (e < NB) lstart[e] = ex;
        ex += c[j];
    }
    __syncthreads();

    // P3: one global reservation per (block,bucket); reset lcur as stage cursor
    for (int b = t; b < NB; b += 256) {
        int h = lcur[b];
        rbase[b] = h ? atomicAdd(&cursor[b], h) : 0;
        lcur[b] = lstart[b];
    }
    __syncthreads();

    // P4: rank via LDS atomics, stage grouped-by-bucket
    for (int i = 0; i < CHUNK / 256; ++i) {
        int p = base + i * 256 + t;
        if (p < P) {
            int m = idx[p];
            int b = m >> BSHIFT;
            int s = atomicAdd(&lcur[b], 1);
            // pack: pid in low 24 bits (P < 16.7M), local pillar in high 8
            stage[s] = (unsigned)p | ((unsigned)(m & (BPILL - 1)) << 24);
        }
    }
    __syncthreads();

    // P5: copy each bucket-run to its contiguous global range
    for (int b = t; b < NB; b += 256) {
        int ls = lstart[b];
        int h  = lcur[b] - ls;
        int rb = rbase[b];
        for (int r = 0; r < h; ++r)
            sorted[rb + r] = stage[ls + r];
    }
}

// ---------------- K3: pool — one block per bucket, LDS accumulator ----------
__device__ __forceinline__ float bcastc(float v, int srclane) {
    return __int_as_float(__builtin_amdgcn_readlane(__float_as_int(v), srclane));
}

__global__ __launch_bounds__(256)
void k_pool(const float* __restrict__ gf,
            const unsigned int* __restrict__ sorted,
            const int* __restrict__ starts,
            const float* __restrict__ W,
            const float* __restrict__ gamma,
            const float* __restrict__ beta,
            const float* __restrict__ rmean,
            const float* __restrict__ rvar,
            float* __restrict__ out, int M) {
    __shared__ unsigned int acc[BPILL * C_OUT];   // 64 KB
    const int t = threadIdx.x;
    const int lane = t & 63;
    const int wv = t >> 6;                        // wave 0..3
    const int bkt = blockIdx.x;

    // zero accumulator (bit 0 == +0.0f, also the empty-pillar/clamp0 identity)
    {
        uint4 z = make_uint4(0u, 0u, 0u, 0u);
        uint4* a4 = (uint4*)acc;
#pragma unroll
        for (int i = 0; i < (BPILL * C_OUT / 4) / 256; ++i)
            a4[i * 256 + t] = z;
    }

    // lane == output channel
    float w[C_IN];
#pragma unroll
    for (int k = 0; k < C_IN; ++k) w[k] = W[k * C_OUT + lane];
    const float inv_std = gamma[lane] * rsqrtf(rvar[lane] + 1e-3f);
    const float bias    = fmaf(-rmean[lane], inv_std, beta[lane]);
    __syncthreads();

    const int s0 = starts[bkt], s1 = starts[bkt + 1];
    const int gdiv = (lane * 205) >> 10;          // lane/5 (exact for 0..63)
    const int gf_f = lane - gdiv * 5;             // lane%5

    for (int b0 = s0 + wv * PPW; b0 < s1; b0 += 4 * PPW) {
        const int nb = min(PPW, s1 - b0);         // wave-uniform
        unsigned v = 0;
        if (lane < nb) v = sorted[b0 + lane];
        int vpid5 = (int)(v & 0xFFFFFFu) * 5;     // float2-unit base offset
        int vml   = (int)(v >> 24);
        float2 x2 = make_float2(0.f, 0.f);
        if (lane < nb * 5) {
            int pb = __shfl(vpid5, gdiv);         // pid of my point group
            x2 = ((const float2*)gf)[pb + gf_f];  // 8B-aligned (40B records)
        }
#pragma unroll
        for (int j = 0; j < PPW; ++j) {
            if (j >= nb) break;                   // wave-uniform
            float y = 0.f;
#pragma unroll
            for (int k = 0; k < C_IN; ++k) {
                float xv = (k & 1) ? bcastc(x2.y, j * 5 + (k >> 1))
                                   : bcastc(x2.x, j * 5 + (k >> 1));
                y = fmaf(xv, w[k], y);
            }
            float h = fmaxf(fmaf(y, inv_std, bias), 0.0f);
            int ml = __builtin_amdgcn_readlane(vml, j);
            atomicMax(&acc[ml * C_OUT + lane], __float_as_uint(h));
        }
    }
    __syncthreads();

    // coalesced write-out (guard for partial last bucket)
    const long gbase4 = (long)bkt * (BPILL * C_OUT / 4);
    const long lim4   = (long)M * (C_OUT / 4);
    uint4* o4 = (uint4*)out;
    const uint4* a4 = (const uint4*)acc;
#pragma unroll
    for (int i = 0; i < (BPILL * C_OUT / 4) / 256; ++i) {
        long o = gbase4 + i * 256 + t;
        if (o < lim4) o4[o] = a4[i * 256 + t];
    }
}

extern "C" void kernel_launch(void* const* d_in, const int* in_sizes, int n_in,
                              void* d_out, int out_size, void* d_ws, size_t ws_size,
                              hipStream_t stream) {
    const float* gf    = (const float*)d_in[0];
    const int*   idx   = (const int*)  d_in[1];
    const float* W     = (const float*)d_in[3];
    const float* gamma = (const float*)d_in[4];
    const float* beta  = (const float*)d_in[5];
    const float* rmean = (const float*)d_in[6];
    const float* rvar  = (const float*)d_in[7];
    float*       out   = (float*)d_out;

    const int P  = in_sizes[0] / C_IN;
    const int M  = out_size / C_OUT;
    const int NB = (M + BPILL - 1) >> BSHIFT;     // 782 for M=200k

    char* ws = (char*)d_ws;
    auto align256 = [](size_t x) { return (x + 255) & ~(size_t)255; };
    int* cursor = (int*)ws;  ws += align256((size_t)MAXNB * 4);        // aliased ghist
    int* starts = (int*)ws;  ws += align256((size_t)(MAXNB + 1) * 4);
    unsigned int* sorted = (unsigned int*)ws;                          // P u32

    const int NBLK = (P + CHUNK - 1) / CHUNK;     // 245

    hipMemsetAsync(cursor, 0, (size_t)NB * 4, stream);
    k_hist <<<NBLK, 256, 0, stream>>>(idx, cursor, P, NB);
    k_scan <<<1,    256, 0, stream>>>(cursor, starts, NB);
    k_split<<<NBLK, 256, 0, stream>>>(idx, cursor, sorted, P, NB);
    k_pool <<<NB,   256, 0, stream>>>(gf, sorted, starts, W, gamma, beta,
                                      rmean, rvar, out, M);
}

// Round 4
// 297.368 us; speedup vs baseline: 1.7010x; 1.4676x over previous
//
#include <hip/hip_runtime.h>

// PillarMaxPooling: Linear(10->64,nobias) -> BN1d(eval,eps=1e-3) -> ReLU ->
// segment_max -> clamp0.
//
// R1: 128M global atomicMax -> atomic-count bound (322 us).
// R2: per-point global scatter sort -> 4.4 GB cross-XCD line ping-pong.
// R3: bucket sort + LDS-accumulator pool works (traffic ~200 MB) but pool is
//     latency-bound: 64 KB acc -> 2 blocks/CU (17% occ), serialized FMA chains.
// R4: 128-pillar buckets (32 KB acc -> 5 blocks/CU), branch-free unrolled
//     12-point body for ILP; split rebuilt as direct scatter with one global
//     reservation per (block,bucket) — no staging, no serial run copy.

#define C_IN   10
#define C_OUT  64
#define BSHIFT 7
#define BPILL  (1 << BSHIFT)     // 128 pillars per bucket
#define MAXNB  2048              // supports M <= 262144
#define SCHUNK 8192              // points per hist/split block
#define PPW    12                // points per wave-iteration in pool

// ---------------- K0: global bucket histogram (LDS-privatized) ----------------
__global__ __launch_bounds__(256)
void k_hist(const int* __restrict__ idx, int* __restrict__ ghist, int P, int NB) {
    __shared__ int lh[MAXNB];
    for (int b = threadIdx.x; b < NB; b += 256) lh[b] = 0;
    __syncthreads();
    const int base = blockIdx.x * SCHUNK;
    for (int i = 0; i < SCHUNK / 256; ++i) {
        int p = base + i * 256 + threadIdx.x;
        if (p < P) atomicAdd(&lh[idx[p] >> BSHIFT], 1);
    }
    __syncthreads();
    for (int b = threadIdx.x; b < NB; b += 256) {
        int h = lh[b];
        if (h) atomicAdd(&ghist[b], h);
    }
}

// ---------------- K1: scan bucket hist -> starts[NB+1] + cursor ----------------
// cursor aliases ghist (in-place). 1 block, 256 threads, 8 entries each.
__global__ __launch_bounds__(256)
void k_scan(int* __restrict__ ghist_cursor, int* __restrict__ starts, int NB) {
    __shared__ int tmp[256];
    const int t = threadIdx.x;
    int c[8]; int tot = 0;
#pragma unroll
    for (int j = 0; j < 8; ++j) {
        int e = t * 8 + j;
        c[j] = (e < NB) ? ghist_cursor[e] : 0;
        tot += c[j];
    }
    tmp[t] = tot; __syncthreads();
#pragma unroll
    for (int off = 1; off < 256; off <<= 1) {
        int x = (t >= off) ? tmp[t - off] : 0;
        __syncthreads();
        tmp[t] += x;
        __syncthreads();
    }
    int ex = tmp[t] - tot;
#pragma unroll
    for (int j = 0; j < 8; ++j) {
        int e = t * 8 + j;
        if (e < NB) { starts[e] = ex; ghist_cursor[e] = ex; }
        ex += c[j];
        if (e == NB - 1) starts[NB] = ex;
    }
}

// ---------------- K2: direct multisplit scatter ----------------
// Local hist -> one global reservation per (block,bucket) -> direct store.
__global__ __launch_bounds__(256)
void k_split(const int* __restrict__ idx, int* __restrict__ cursor,
             unsigned int* __restrict__ sorted, int P, int NB) {
    __shared__ int lh[MAXNB];     // hist, then reused as rank cursor
    __shared__ int rbase[MAXNB];
    const int t = threadIdx.x;
    const int base = blockIdx.x * SCHUNK;

    for (int b = t; b < NB; b += 256) lh[b] = 0;
    __syncthreads();
    for (int i = 0; i < SCHUNK / 256; ++i) {
        int p = base + i * 256 + t;
        if (p < P) atomicAdd(&lh[idx[p] >> BSHIFT], 1);
    }
    __syncthreads();
    // reserve global ranges; reset lh to 0 for rank phase (same owner thread)
    for (int b = t; b < NB; b += 256) {
        int h = lh[b];
        rbase[b] = h ? atomicAdd(&cursor[b], h) : 0;
        lh[b] = 0;
    }
    __syncthreads();
    for (int i = 0; i < SCHUNK / 256; ++i) {
        int p = base + i * 256 + t;
        if (p < P) {
            int m = idx[p];
            int b = m >> BSHIFT;
            int s = atomicAdd(&lh[b], 1);
            // pack: pid in low 24 bits (P < 16.7M), local pillar in high bits
            sorted[rbase[b] + s] = (unsigned)p | ((unsigned)(m & (BPILL - 1)) << 24);
        }
    }
}

// ---------------- K3: pool — one block per bucket, 32 KB LDS accumulator ------
__device__ __forceinline__ float bcastc(float v, int srclane) {
    return __int_as_float(__builtin_amdgcn_readlane(__float_as_int(v), srclane));
}

__global__ __launch_bounds__(256)
void k_pool(const float* __restrict__ gf,
            const unsigned int* __restrict__ sorted,
            const int* __restrict__ starts,
            const float* __restrict__ W,
            const float* __restrict__ gamma,
            const float* __restrict__ beta,
            const float* __restrict__ rmean,
            const float* __restrict__ rvar,
            float* __restrict__ out, int M) {
    __shared__ unsigned int acc[BPILL * C_OUT];   // 32 KB -> 5 blocks/CU
    const int t = threadIdx.x;
    const int lane = t & 63;
    const int wv = t >> 6;

    // zero accumulator (+0.0f bits == atomicMax identity == clamp0/empty value)
    {
        uint4 z = make_uint4(0u, 0u, 0u, 0u);
        uint4* a4 = (uint4*)acc;
#pragma unroll
        for (int i = 0; i < (BPILL * C_OUT / 4) / 256; ++i)
            a4[i * 256 + t] = z;
    }

    // lane == output channel
    float w[C_IN];
#pragma unroll
    for (int k = 0; k < C_IN; ++k) w[k] = W[k * C_OUT + lane];
    const float inv_std = gamma[lane] * rsqrtf(rvar[lane] + 1e-3f);
    const float bias    = fmaf(-rmean[lane], inv_std, beta[lane]);
    __syncthreads();

    const int s0 = starts[blockIdx.x], s1 = starts[blockIdx.x + 1];
    const int gdiv = (lane * 205) >> 10;          // lane/5 (exact for 0..63)
    const int gf_f = lane - gdiv * 5;             // lane%5
    const float2* gf2 = (const float2*)gf;

#define POOL_POINT(J)                                                       \
    {                                                                       \
        float y = 0.f;                                                      \
        _Pragma("unroll")                                                   \
        for (int k = 0; k < C_IN; ++k) {                                    \
            float xv = (k & 1) ? bcastc(x2.y, (J) * 5 + (k >> 1))           \
                               : bcastc(x2.x, (J) * 5 + (k >> 1));          \
            y = fmaf(xv, w[k], y);                                          \
        }                                                                   \
        float h = fmaxf(fmaf(y, inv_std, bias), 0.0f);                      \
        int ml = __builtin_amdgcn_readlane(vml, (J));                       \
        atomicMax(&acc[ml * C_OUT + lane], __float_as_uint(h));             \
    }

    for (int b0 = s0 + wv * PPW; b0 < s1; b0 += 4 * PPW) {
        const int nb = min(PPW, s1 - b0);         // wave-uniform
        unsigned v = 0;
        if (lane < nb) v = sorted[b0 + lane];
        int vpid5 = (int)(v & 0xFFFFFFu) * 5;     // float2-unit base offset
        int vml   = (int)(v >> 24);
        float2 x2 = make_float2(0.f, 0.f);
        if (lane < nb * 5) {
            int pb = __shfl(vpid5, gdiv);
            x2 = gf2[pb + gf_f];                  // 8B-aligned (40B records)
        }
        if (nb == PPW) {
            // branch-free unrolled body: 12 independent chains -> ILP
#pragma unroll
            for (int j = 0; j < PPW; ++j) POOL_POINT(j)
        } else {
            for (int j = 0; j < nb; ++j) POOL_POINT(j)   // uniform tail
        }
    }
#undef POOL_POINT
    __syncthreads();

    // coalesced write-out (guard for partial last bucket)
    const long gbase4 = (long)blockIdx.x * (BPILL * C_OUT / 4);
    const long lim4   = (long)M * (C_OUT / 4);
    uint4* o4 = (uint4*)out;
    const uint4* a4 = (const uint4*)acc;
#pragma unroll
    for (int i = 0; i < (BPILL * C_OUT / 4) / 256; ++i) {
        long o = gbase4 + i * 256 + t;
        if (o < lim4) o4[o] = a4[i * 256 + t];
    }
}

extern "C" void kernel_launch(void* const* d_in, const int* in_sizes, int n_in,
                              void* d_out, int out_size, void* d_ws, size_t ws_size,
                              hipStream_t stream) {
    const float* gf    = (const float*)d_in[0];
    const int*   idx   = (const int*)  d_in[1];
    const float* W     = (const float*)d_in[3];
    const float* gamma = (const float*)d_in[4];
    const float* beta  = (const float*)d_in[5];
    const float* rmean = (const float*)d_in[6];
    const float* rvar  = (const float*)d_in[7];
    float*       out   = (float*)d_out;

    const int P  = in_sizes[0] / C_IN;
    const int M  = out_size / C_OUT;
    const int NB = (M + BPILL - 1) >> BSHIFT;     // 1563 for M=200k

    char* ws = (char*)d_ws;
    auto align256 = [](size_t x) { return (x + 255) & ~(size_t)255; };
    int* cursor = (int*)ws;  ws += align256((size_t)MAXNB * 4);        // aliased ghist
    int* starts = (int*)ws;  ws += align256((size_t)(MAXNB + 1) * 4);
    unsigned int* sorted = (unsigned int*)ws;                          // P u32

    const int NBLK = (P + SCHUNK - 1) / SCHUNK;   // 245

    hipMemsetAsync(cursor, 0, (size_t)NB * 4, stream);
    k_hist <<<NBLK, 256, 0, stream>>>(idx, cursor, P, NB);
    k_scan <<<1,    256, 0, stream>>>(cursor, starts, NB);
    k_split<<<NBLK, 256, 0, stream>>>(idx, cursor, sorted, P, NB);
    k_pool <<<NB,   256, 0, stream>>>(gf, sorted, starts, W, gamma, beta,
                                      rmean, rvar, out, M);
}